// Round 1
// 413.839 us; speedup vs baseline: 1.3830x; 1.3830x over previous
//
#include <hip/hip_runtime.h>

// Correlation cost volume: B=4, C=256, H=W=192, MAX_DISP=4 -> 81 displacements.
// out[b, dy*9+dx, y, x] = (1/C) * sum_c F[b,c,y,x] * Spad[b,c,y+dy-4,x+dx-4]
//
// R1: software-pipelined chunk loop (register prefetch 1 chunk ahead,
//     double-buffered LDS, 1 barrier/chunk). CC 8->4 so 2x LDS buffers keep
//     total at 36,352 B (3 blocks/CU, thread-capped). OOB halo slots zeroed
//     once; staging index math hoisted out of the loop.

#define MAXD 4
#define WINW 9
#define NDISP 81

constexpr int B_ = 4, C_ = 256, H_ = 192, W_ = 192;
constexpr int TH = 4;                    // output rows per block
constexpr int TW = 64;                   // output cols per block
constexpr int CC = 4;                    // channels staged per chunk
constexpr int NCHUNK = C_ / CC;          // 64
constexpr int SROWS = TH + 2 * MAXD;     // 12
constexpr int SCOLS = TW + 2 * MAXD;     // 72
constexpr int F_STRIDE = 68;             // padded from 64 (bank spread)
constexpr int S_STRIDE = 72;
constexpr int F_CH = TH * F_STRIDE;      // 272 floats per staged channel
constexpr int S_CH = SROWS * S_STRIDE;   // 864 floats per staged channel
constexpr int FBUF = CC * F_CH;          // 1088 floats per half
constexpr int SBUF = CC * S_CH;          // 3456 floats per half
constexpr int NTHREADS = 576;            // 9 waves: wave id == dy
constexpr int NF4 = CC * TH * (TW / 4);         // 256 float4 per chunk (F)
constexpr int NS4 = CC * SROWS * (SCOLS / 4);   // 864 float4 per chunk (S)

__global__ __launch_bounds__(NTHREADS)
void corr_kernel(const float* __restrict__ F, const float* __restrict__ S,
                 float* __restrict__ O) {
    __shared__ __align__(16) float ldsF[2 * FBUF];   // 8.5 KB
    __shared__ __align__(16) float ldsS[2 * SBUF];   // 27 KB

    const int tid  = threadIdx.x;
    const int y0   = blockIdx.x * TH;
    const int x0   = blockIdx.y * TW;
    const int b    = blockIdx.z;
    const int dy   = tid >> 6;           // wave index = dy in [0,9)
    const int lane = tid & 63;
    const int xg   = lane & 15;          // x-group of 4 pixels
    const int yth  = lane >> 4;          // row within tile, [0,4)

    const long planeHW  = (long)H_ * W_;  // 36864
    const long chunkStep = (long)CC * planeHW;
    const float* Fb = F + (long)b * C_ * planeHW;
    const float* Sb = S + (long)b * C_ * planeHW;

    // ---- chunk-invariant staging decomposition (hoisted) ----
    // F slot: one float4 for tid < 256, always in-bounds.
    const bool fAct = (tid < NF4);
    const int  fcc  = tid >> 6;
    const int  fyr  = (tid >> 4) & 3;
    const int  fcg  = tid & 15;
    const int  fLds = fcc * F_CH + fyr * F_STRIDE + 4 * fcg;
    const float* fPtr0 = Fb + (long)fcc * planeHW + (long)(y0 + fyr) * W_ + (x0 + 4 * fcg);

    // S slot 0: i = tid (< 864 always -> active for every thread).
    const int  s0cc  = tid / (SROWS * (SCOLS / 4));            // /216
    const int  s0rem = tid - s0cc * (SROWS * (SCOLS / 4));
    const int  s0r   = s0rem / (SCOLS / 4);                    // /18
    const int  s0cg  = s0rem - s0r * (SCOLS / 4);
    const int  s0ys  = y0 - MAXD + s0r;
    const int  s0xs  = x0 - MAXD + 4 * s0cg;
    const bool s0In  = ((unsigned)s0ys < (unsigned)H_) &&
                       ((unsigned)s0xs <= (unsigned)(W_ - 4));
    const int  s0Lds = s0cc * S_CH + s0r * S_STRIDE + 4 * s0cg;
    const float* s0Ptr0 = Sb + (long)s0cc * planeHW + (long)s0ys * W_ + s0xs;

    // S slot 1: i = tid + 576, active only for tid < 288.
    const int  i1    = tid + NTHREADS;
    const bool s1Act = (i1 < NS4);
    const int  s1cc  = i1 / (SROWS * (SCOLS / 4));
    const int  s1rem = i1 - s1cc * (SROWS * (SCOLS / 4));
    const int  s1r   = s1rem / (SCOLS / 4);
    const int  s1cg  = s1rem - s1r * (SCOLS / 4);
    const int  s1ys  = y0 - MAXD + s1r;
    const int  s1xs  = x0 - MAXD + 4 * s1cg;
    const bool s1In  = s1Act && ((unsigned)s1ys < (unsigned)H_) &&
                       ((unsigned)s1xs <= (unsigned)(W_ - 4));
    const int  s1Lds = s1cc * S_CH + s1r * S_STRIDE + 4 * s1cg;
    const float* s1Ptr0 = Sb + (long)s1cc * planeHW + (long)s1ys * W_ + s1xs;

    // ---- zero the OOB halo slots ONCE (both halves), never rewritten ----
    const float4 z4 = make_float4(0.f, 0.f, 0.f, 0.f);
    if (!s0In) {
        *(float4*)(ldsS + s0Lds) = z4;
        *(float4*)(ldsS + SBUF + s0Lds) = z4;
    }
    if (s1Act && !s1In) {
        *(float4*)(ldsS + s1Lds) = z4;
        *(float4*)(ldsS + SBUF + s1Lds) = z4;
    }

    // ---- prefetch registers + pipelined staging helpers ----
    float4 pf, ps0, ps1;
    const float* fNext  = fPtr0;
    const float* s0Next = s0Ptr0;
    const float* s1Next = s1Ptr0;

    auto loadRegs = [&]() {               // issue-early: global -> regs
        if (fAct) pf  = *(const float4*)fNext;
        if (s0In) ps0 = *(const float4*)s0Next;
        if (s1In) ps1 = *(const float4*)s1Next;
        fNext  += chunkStep;
        s0Next += chunkStep;
        s1Next += chunkStep;
    };

    auto writeLds = [&](int half) {       // write-late: regs -> LDS
        float* wF = ldsF + half * FBUF;
        float* wS = ldsS + half * SBUF;
        if (fAct) *(float4*)(wF + fLds)  = pf;
        if (s0In) *(float4*)(wS + s0Lds) = ps0;
        if (s1In) *(float4*)(wS + s1Lds) = ps1;
    };

    // ---- accumulators ----
    float acc[WINW][4];
    #pragma unroll
    for (int dx = 0; dx < WINW; ++dx)
        #pragma unroll
        for (int j = 0; j < 4; ++j) acc[dx][j] = 0.f;

    auto computeChunk = [&](int half) {
        const float* bF = ldsF + half * FBUF + yth * F_STRIDE + 4 * xg;
        const float* bS = ldsS + half * SBUF + (yth + dy) * S_STRIDE + 4 * xg;
        #pragma unroll
        for (int cc = 0; cc < CC; ++cc) {
            const float4 f  = *(const float4*)(bF + cc * F_CH);
            const float4 w0 = *(const float4*)(bS + cc * S_CH);
            const float4 w1 = *(const float4*)(bS + cc * S_CH + 4);
            const float4 w2 = *(const float4*)(bS + cc * S_CH + 8);
            const float w[12] = {w0.x, w0.y, w0.z, w0.w,
                                 w1.x, w1.y, w1.z, w1.w,
                                 w2.x, w2.y, w2.z, w2.w};
            #pragma unroll
            for (int dx = 0; dx < WINW; ++dx) {
                acc[dx][0] += f.x * w[dx];
                acc[dx][1] += f.y * w[dx + 1];
                acc[dx][2] += f.z * w[dx + 2];
                acc[dx][3] += f.w * w[dx + 3];
            }
        }
    };

    // ---- pipelined main loop: 1 barrier per chunk ----
    loadRegs();          // chunk 0 -> regs
    writeLds(0);         // chunk 0 -> LDS half 0
    loadRegs();          // chunk 1 -> regs (in flight during first compute)
    __syncthreads();

    for (int k = 0; k < NCHUNK; ++k) {
        const int cur = k & 1;
        computeChunk(cur);
        if (k + 1 < NCHUNK) {
            writeLds(cur ^ 1);                  // chunk k+1 regs -> other half
            if (k + 2 < NCHUNK) loadRegs();     // issue chunk k+2 loads
            __syncthreads();
        }
    }

    // ---- epilogue: 9 coalesced float4 stores per thread ----
    const float scale = 1.0f / (float)C_;
    #pragma unroll
    for (int dx = 0; dx < WINW; ++dx) {
        float4 o;
        o.x = acc[dx][0] * scale;
        o.y = acc[dx][1] * scale;
        o.z = acc[dx][2] * scale;
        o.w = acc[dx][3] * scale;
        const int d = dy * WINW + dx;
        float* dst = O + ((long)(b * NDISP + d) * H_ + (y0 + yth)) * W_ + x0 + 4 * xg;
        *(float4*)dst = o;
    }
}

extern "C" void kernel_launch(void* const* d_in, const int* in_sizes, int n_in,
                              void* d_out, int out_size, void* d_ws, size_t ws_size,
                              hipStream_t stream) {
    const float* F = (const float*)d_in[0];
    const float* S = (const float*)d_in[1];
    float* O = (float*)d_out;
    dim3 grid(H_ / TH, W_ / TW, B_);   // 48 x 3 x 4 = 576 blocks
    dim3 block(NTHREADS);
    corr_kernel<<<grid, block, 0, stream>>>(F, S, O);
}